// Round 2
// baseline (80.707 us; speedup 1.0000x reference)
//
#include <hip/hip_runtime.h>

// FFM pairwise cross-term layer.
// out[b, p, d] = W[jj[p], adj[b, ii[p]], d] * W[ii[p], adj[b, jj[p]], d]
// B=8192, F=23, P=F*(F-1)/2=253, D=32, VOCAB=190001, fp32 throughout.
//
// Memory analysis: output = 265 MB HBM write (the floor). Gathered W rows
// come from a ~6.5 MB working set (x < 100 -> only 2200 rows/table) -> L2/L3
// hits. One block per batch element; precompute the 253 row offsets in LDS;
// inner loop is perfectly coalesced: 2x float4 load (cache-hit) + mul +
// nontemporal float4 store (keeps the hot W set in L2 instead of being
// thrashed by the 265 MB write stream).

#define NF 23
#define NP 253             // 23*22/2
#define VOCAB 190001
#define F4_PER_B (NP * 8)  // 253 pairs * 8 float4 (D=32)

typedef float f32x4 __attribute__((ext_vector_type(4)));

__global__ __launch_bounds__(256) void ffm_cross_kernel(
    const int* __restrict__ x,
    const int* __restrict__ offs,
    const float* __restrict__ W,
    float* __restrict__ out)
{
    __shared__ int adj_s[NF];
    __shared__ unsigned int rowA[NP];  // float4-index of W[jj, adj[ii], 0]
    __shared__ unsigned int rowB[NP];  // float4-index of W[ii, adj[jj], 0]

    const int b   = blockIdx.x;
    const int tid = threadIdx.x;

    if (tid < NF) adj_s[tid] = x[b * NF + tid] + offs[tid];
    __syncthreads();

    if (tid < NP) {
        // unrank pair p -> (i, j), row-major triu order: (0,1),(0,2),...,(21,22)
        int rem = tid, i = 0;
        while (rem >= (NF - 1 - i)) { rem -= (NF - 1 - i); ++i; }
        int j = i + 1 + rem;
        // max index: (22*190001 + 190000)*8 < 2^32 -> u32 ok
        rowA[tid] = ((unsigned)j * (unsigned)VOCAB + (unsigned)adj_s[i]) * 8u;
        rowB[tid] = ((unsigned)i * (unsigned)VOCAB + (unsigned)adj_s[j]) * 8u;
    }
    __syncthreads();

    const f32x4* __restrict__ W4 = reinterpret_cast<const f32x4*>(W);
    f32x4* __restrict__ O4 =
        reinterpret_cast<f32x4*>(out) + (size_t)b * F4_PER_B;

    #pragma unroll
    for (int k = 0; k < 8; ++k) {
        int idx = tid + k * 256;
        if (idx < F4_PER_B) {
            int p  = idx >> 3;
            int d4 = idx & 7;
            f32x4 a = W4[(size_t)rowA[p] + d4];
            f32x4 c = W4[(size_t)rowB[p] + d4];
            f32x4 r = a * c;
            __builtin_nontemporal_store(r, &O4[idx]);
        }
    }
}

extern "C" void kernel_launch(void* const* d_in, const int* in_sizes, int n_in,
                              void* d_out, int out_size, void* d_ws, size_t ws_size,
                              hipStream_t stream)
{
    const int*   x    = (const int*)d_in[0];    // [8192, 23] int32
    const int*   offs = (const int*)d_in[1];    // [23] int32
    const float* W    = (const float*)d_in[2];  // [23, 190001, 32] fp32
    float*       out  = (float*)d_out;          // [8192, 253, 32] fp32

    ffm_cross_kernel<<<8192, 256, 0, stream>>>(x, offs, W, out);
}